// Round 2
// baseline (78.924 us; speedup 1.0000x reference)
//
#include <hip/hip_runtime.h>

#define LORENZ_DT 0.02f

// Native clang vector type: layout-compatible with float4, accepted by
// __builtin_nontemporal_load/store (HIP's float4 class is not).
typedef float vfloat4 __attribute__((ext_vector_type(4)));

__device__ __forceinline__ void lorenz_one(float x0, float x1, float x2,
                                           float& o0, float& o1, float& o2) {
    // A*dt; only a12/a21 depend on x0. a02 = a20 = 0 structurally.
    const float a00 = -10.0f * LORENZ_DT;
    const float a01 =  10.0f * LORENZ_DT;
    const float a10 =  28.0f * LORENZ_DT;
    const float a11 =  -1.0f * LORENZ_DT;
    const float a22 = (-8.0f / 3.0f) * LORENZ_DT;
    const float a12 = -x0 * LORENZ_DT;
    const float a21 =  x0 * LORENZ_DT;

    // F = I + sum_{j=1..5} (A dt)^j / j!, term recurrence: t <- (t @ A dt)/j
    float t00 = 1.f, t01 = 0.f, t02 = 0.f;
    float t10 = 0.f, t11 = 1.f, t12 = 0.f;
    float t20 = 0.f, t21 = 0.f, t22 = 1.f;
    float F00 = 1.f, F01 = 0.f, F02 = 0.f;
    float F10 = 0.f, F11 = 1.f, F12 = 0.f;
    float F20 = 0.f, F21 = 0.f, F22 = 1.f;

#pragma unroll
    for (int j = 1; j <= 5; ++j) {
        const float inv = 1.0f / (float)j;  // folds to a literal after unroll
        float n00 = (t00 * a00 + t01 * a10) * inv;
        float n01 = (t00 * a01 + t01 * a11 + t02 * a21) * inv;
        float n02 = (t01 * a12 + t02 * a22) * inv;
        float n10 = (t10 * a00 + t11 * a10) * inv;
        float n11 = (t10 * a01 + t11 * a11 + t12 * a21) * inv;
        float n12 = (t11 * a12 + t12 * a22) * inv;
        float n20 = (t20 * a00 + t21 * a10) * inv;
        float n21 = (t20 * a01 + t21 * a11 + t22 * a21) * inv;
        float n22 = (t21 * a12 + t22 * a22) * inv;
        t00 = n00; t01 = n01; t02 = n02;
        t10 = n10; t11 = n11; t12 = n12;
        t20 = n20; t21 = n21; t22 = n22;
        F00 += t00; F01 += t01; F02 += t02;
        F10 += t10; F11 += t11; F12 += t12;
        F20 += t20; F21 += t21; F22 += t22;
    }

    o0 = F00 * x0 + F01 * x1 + F02 * x2;
    o1 = F10 * x0 + F11 * x1 + F12 * x2;
    o2 = F20 * x0 + F21 * x1 + F22 * x2;
}

// Geometry: 256 threads/block, 4 elements/thread -> 1024 elements = 3072 floats
// = 768 float4 per block chunk (12 KB each way).
//
// Staging layout: padded float4 slot s(i) = i + i/24 (one float4 pad every 24).
// - Coalesced phase: lane t accesses slot s(t + 256j) -> bank-group spread ~2-way (free).
// - Compute phase: thread t's 12 floats start at word 12t + 4*(t>>3); groups
//   (3t + (t>>3)) mod 8 cover all 8 bank-groups per 8-lane octave -> conflict-free
//   ds_read_b128/ds_write_b128.
// Derivation checked: float q = 12t+k lives in float4 i = 3t + k/4; 3t..3t+2 never
// crosses a 24-boundary, so padded word = 12t + k + 4*(t>>3) exactly.

#define BLOCK 256
#define EPT 4
#define ELEMS_PER_BLOCK (BLOCK * EPT)          // 1024
#define F4_PER_BLOCK (ELEMS_PER_BLOCK * 3 / 4) // 768
#define F4_PADDED (F4_PER_BLOCK + F4_PER_BLOCK / 24) // 800

__device__ __forceinline__ int pad4(int i) { return i + i / 24; }

__global__ __launch_bounds__(256) void lorenz_kernel(const float* __restrict__ x,
                                                     float* __restrict__ out, int n) {
    const int tid = threadIdx.x;
    const int blockElemBase = blockIdx.x * ELEMS_PER_BLOCK;

    __shared__ vfloat4 lbuf[F4_PADDED];
    float* lfs = (float*)lbuf;

    if (blockElemBase + ELEMS_PER_BLOCK <= n) {
        // ---- fast path: full 1024-element chunk, fully coalesced ----
        const vfloat4* x4 = (const vfloat4*)x;
        vfloat4* o4 = (vfloat4*)out;
        const size_t b4 = (size_t)blockIdx.x * F4_PER_BLOCK;

        // stage in: 3 contiguous 4KB wave-transactions, non-temporal
#pragma unroll
        for (int j = 0; j < 3; ++j) {
            vfloat4 v = __builtin_nontemporal_load(&x4[b4 + tid + BLOCK * j]);
            lbuf[pad4(tid + BLOCK * j)] = v;
        }
        __syncthreads();

        // per-thread gather of its 4 elements (conflict-free b128 reads)
        const int wb = 12 * tid + 4 * (tid >> 3);
        float xs[12], os[12];
#pragma unroll
        for (int k = 0; k < 12; ++k) xs[k] = lfs[wb + k];

#pragma unroll
        for (int e = 0; e < 4; ++e) {
            lorenz_one(xs[e * 3 + 0], xs[e * 3 + 1], xs[e * 3 + 2],
                       os[e * 3 + 0], os[e * 3 + 1], os[e * 3 + 2]);
        }

        // scatter back to own slots (disjoint per-thread -> no barrier needed before)
#pragma unroll
        for (int k = 0; k < 12; ++k) lfs[wb + k] = os[k];
        __syncthreads();

        // stage out: 3 contiguous 4KB wave-transactions, non-temporal
#pragma unroll
        for (int j = 0; j < 3; ++j) {
            vfloat4 v = lbuf[pad4(tid + BLOCK * j)];
            __builtin_nontemporal_store(v, &o4[b4 + tid + BLOCK * j]);
        }
    } else {
        // ---- tail block: direct (possibly partial) path ----
        const int g = blockElemBase / EPT + tid;  // group of 4 elements
        const int base = g * 4;
        if (base >= n) return;

        if (base + 4 <= n) {
            const float4* xv = (const float4*)x;
            float4* ov = (float4*)out;
            float4 va = xv[g * 3 + 0];
            float4 vb = xv[g * 3 + 1];
            float4 vc = xv[g * 3 + 2];
            float xs[12] = {va.x, va.y, va.z, va.w,
                            vb.x, vb.y, vb.z, vb.w,
                            vc.x, vc.y, vc.z, vc.w};
            float os[12];
#pragma unroll
            for (int e = 0; e < 4; ++e) {
                lorenz_one(xs[e * 3 + 0], xs[e * 3 + 1], xs[e * 3 + 2],
                           os[e * 3 + 0], os[e * 3 + 1], os[e * 3 + 2]);
            }
            ov[g * 3 + 0] = make_float4(os[0], os[1], os[2], os[3]);
            ov[g * 3 + 1] = make_float4(os[4], os[5], os[6], os[7]);
            ov[g * 3 + 2] = make_float4(os[8], os[9], os[10], os[11]);
        } else {
            for (int e = base; e < n; ++e) {
                float x0 = x[e * 3 + 0], x1 = x[e * 3 + 1], x2 = x[e * 3 + 2];
                float o0, o1, o2;
                lorenz_one(x0, x1, x2, o0, o1, o2);
                out[e * 3 + 0] = o0;
                out[e * 3 + 1] = o1;
                out[e * 3 + 2] = o2;
            }
        }
    }
}

extern "C" void kernel_launch(void* const* d_in, const int* in_sizes, int n_in,
                              void* d_out, int out_size, void* d_ws, size_t ws_size,
                              hipStream_t stream) {
    const float* x = (const float*)d_in[0];
    float* out = (float*)d_out;
    const int n = in_sizes[0] / 3;  // batch count (2,000,000)
    const int grid = (n + ELEMS_PER_BLOCK - 1) / ELEMS_PER_BLOCK;
    lorenz_kernel<<<grid, BLOCK, 0, stream>>>(x, out, n);
}